// Round 7
// baseline (85.392 us; speedup 1.0000x reference)
//
#include <hip/hip_runtime.h>

// RoIAlign: features (B=4, C=256, H=200, W=200) f32, rois (R,5) f32,
// out (R, C, 7, 7) f32.  SCALE=0.25, AH=AW=7, legacy (x2-x1+1) semantics.
//
// Round-6 = polished round-4 (direct scattered gather — measured to be within
// ~15% of the NCHW line-touch floor):
//  - block = (roi, 32-channel group); 49-entry geometry table cached in LDS
//    (784 B) -> table reads off the TA path.
//  - table entry carries the precomputed plane-0 word offset.
//  - each thread computes 2 outputs (ch, ch+16): shared table entry, shared
//    weights, 8 loads in flight.
//  - XCD channel affinity (bid&7), spatial roi sort, nontemporal stores kept.

#define C_     256
#define H_     200
#define W_     200
#define HW_    40000
#define NBIN   49
#define SCALE_ 0.25f
#define NKEY   256    // 4 batches x 8 y-tiles x 8 x-tiles

// ---------------- kernel 0: locality sort (counting sort, 256 buckets) -----
__global__ __launch_bounds__(1024) void roi_sortkey(
        const float* __restrict__ rois, int* __restrict__ perm, int R) {
    __shared__ int cnt[NKEY];
    __shared__ int off[NKEY];
    int t = threadIdx.x;
    if (t < NKEY) cnt[t] = 0;
    __syncthreads();
    for (int i = t; i < R; i += 1024) {
        const float* rr = rois + (size_t)i * 5;
        int b = ((int)rr[0]) & 3;
        float xc = (rr[1] + rr[3]) * 0.5f * SCALE_;
        float yc = (rr[2] + rr[4]) * 0.5f * SCALE_;
        int xt = min(7, max(0, (int)(xc * 0.04f)));
        int yt = min(7, max(0, (int)(yc * 0.04f)));
        atomicAdd(&cnt[(b << 6) | (yt << 3) | xt], 1);
    }
    __syncthreads();
    if (t == 0) {
        int s = 0;
        for (int k = 0; k < NKEY; ++k) { off[k] = s; s += cnt[k]; }
    }
    __syncthreads();
    for (int i = t; i < R; i += 1024) {
        const float* rr = rois + (size_t)i * 5;
        int b = ((int)rr[0]) & 3;
        float xc = (rr[1] + rr[3]) * 0.5f * SCALE_;
        float yc = (rr[2] + rr[4]) * 0.5f * SCALE_;
        int xt = min(7, max(0, (int)(xc * 0.04f)));
        int yt = min(7, max(0, (int)(yc * 0.04f)));
        int pos = atomicAdd(&off[(b << 6) | (yt << 3) | xt], 1);
        perm[pos] = i;
    }
}

// ---------------- kernel 1: per-(roi,bin) geometry table -------------------
// table[i] = { hr, wr, as_float(plane0 word offset), validf }
__global__ __launch_bounds__(256) void roi_precompute(
        const float* __restrict__ rois, float4* __restrict__ table, int nbins) {
    int i = blockIdx.x * 256 + threadIdx.x;
    if (i >= nbins) return;
    int r   = i / NBIN;
    int bin = i - r * NBIN;
    int ph  = bin / 7;
    int pw  = bin - ph * 7;

    float bf = rois[r * 5 + 0];
    float x1 = rois[r * 5 + 1] * SCALE_;
    float y1 = rois[r * 5 + 2] * SCALE_;
    float x2 = rois[r * 5 + 3] * SCALE_;
    float y2 = rois[r * 5 + 4] * SCALE_;

    float bin_h = fmaxf(y2 - y1 + 1.0f, 0.0f) * (1.0f / 6.0f);
    float bin_w = fmaxf(x2 - x1 + 1.0f, 0.0f) * (1.0f / 6.0f);

    float h = y1 + (float)ph * bin_h;
    float w = x1 + (float)pw * bin_w;

    bool valid = (h >= 0.0f) && (h < (float)H_) && (w >= 0.0f) && (w < (float)W_);

    float h0f = fmaxf(fminf(floorf(h), (float)(H_ - 2)), 0.0f);
    float w0f = fmaxf(fminf(floorf(w), (float)(W_ - 2)), 0.0f);
    float hr = h - h0f;
    float wr = w - w0f;
    int b  = (int)bf;
    int off0 = b * C_ * HW_ + (int)h0f * W_ + (int)w0f;   // < 2^31

    table[i] = make_float4(hr, wr, __int_as_float(off0), valid ? 1.0f : 0.0f);
}

// ---------------- kernel 2: main gather -------------------------------------
// grid = R*8 blocks; g = bid&7 (XCD affinity), pos = bid>>3, roi = perm[pos].
// Block covers channels [g*32, g*32+32): item o = ci*49+bin handles ch c0+ci
// and c0+ci+16 (2 outputs, shared geometry).
__global__ __launch_bounds__(256) void roi_main(
        const float* __restrict__ feat, const float4* __restrict__ table,
        const int* __restrict__ perm, float* __restrict__ out, int R) {
    __shared__ float4 sT[NBIN];
    int bid = blockIdx.x;
    int g   = bid & 7;
    int pos = bid >> 3;
    int r   = perm[pos];
    int tid = threadIdx.x;
    if (tid < NBIN) sT[tid] = table[(size_t)r * NBIN + tid];
    __syncthreads();

    int c0 = g * 32;
    size_t outbase = ((size_t)r * C_ + c0) * NBIN;

    #pragma unroll
    for (int k = 0; k < 4; ++k) {
        int o = tid + k * 256;
        if (o < 16 * NBIN) {
            int ci  = o / NBIN;
            int bin = o - ci * NBIN;
            float4 e = sT[bin];
            float hr = e.x, wr = e.y, vf = e.w;
            int   off = __float_as_int(e.z) + (c0 + ci) * HW_;

            const float* pA = feat + off;             // ch = c0+ci
            const float* pB = pA + 16 * HW_;          // ch = c0+ci+16
            float a00 = pA[0], a01 = pA[1], a10 = pA[W_], a11 = pA[W_ + 1];
            float b00 = pB[0], b01 = pB[1], b10 = pB[W_], b11 = pB[W_ + 1];

            float at = fmaf(wr, a01 - a00, a00);
            float ab = fmaf(wr, a11 - a10, a10);
            float bt = fmaf(wr, b01 - b00, b00);
            float bb = fmaf(wr, b11 - b10, b10);
            float va = fmaf(hr, ab - at, at) * vf;
            float vb = fmaf(hr, bb - bt, bt) * vf;

            __builtin_nontemporal_store(va, &out[outbase + o]);
            __builtin_nontemporal_store(vb, &out[outbase + o + 16 * NBIN]);
        }
    }
}

// ---------------- fallback: fused (no workspace) ----------------------------
__global__ __launch_bounds__(256) void roi_fused(
        const float* __restrict__ feat, const float* __restrict__ rois,
        float* __restrict__ out, int total) {
    int idx = blockIdx.x * 256 + threadIdx.x;
    if (idx >= total) return;

    unsigned u   = (unsigned)idx;
    unsigned bin = u % (unsigned)NBIN;
    unsigned rc  = u / (unsigned)NBIN;
    unsigned c   = rc & 255u;
    unsigned r   = rc >> 8;
    int ph = bin / 7;
    int pw = bin - ph * 7;

    float bf = rois[r * 5 + 0];
    float x1 = rois[r * 5 + 1] * SCALE_;
    float y1 = rois[r * 5 + 2] * SCALE_;
    float x2 = rois[r * 5 + 3] * SCALE_;
    float y2 = rois[r * 5 + 4] * SCALE_;

    float roi_w = fmaxf(x2 - x1 + 1.0f, 0.0f);
    float roi_h = fmaxf(y2 - y1 + 1.0f, 0.0f);
    float h = y1 + (float)ph * (roi_h / 6.0f);
    float w = x1 + (float)pw * (roi_w / 6.0f);

    float valid = ((h >= 0.0f) && (h < (float)H_) && (w >= 0.0f) && (w < (float)W_))
                      ? 1.0f : 0.0f;

    float h0f = fmaxf(fminf(floorf(h), (float)(H_ - 2)), 0.0f);
    float w0f = fmaxf(fminf(floorf(w), (float)(W_ - 2)), 0.0f);
    int h0 = (int)h0f;
    int w0 = (int)w0f;
    float hr = h - h0f;
    float wr = w - w0f;
    int b = (int)bf;

    const float* p = feat + ((size_t)(b * C_ + (int)c)) * (size_t)HW_
                          + (size_t)(h0 * W_ + w0);
    float v00 = p[0];
    float v01 = p[1];
    float v10 = p[W_];
    float v11 = p[W_ + 1];

    float top = fmaf(wr, v01 - v00, v00);
    float bot = fmaf(wr, v11 - v10, v10);
    float val = fmaf(hr, bot - top, top);

    out[idx] = val * valid;
}

extern "C" void kernel_launch(void* const* d_in, const int* in_sizes, int n_in,
                              void* d_out, int out_size, void* d_ws, size_t ws_size,
                              hipStream_t stream) {
    const float* feat = (const float*)d_in[0];
    const float* rois = (const float*)d_in[1];
    float* out = (float*)d_out;

    int R     = in_sizes[1] / 5;
    int nbins = R * NBIN;
    int total = R * C_ * NBIN;   // == out_size

    // workspace layout: perm (R ints), then 16B-aligned table (R*49 float4)
    size_t perm_bytes  = ((size_t)R * sizeof(int) + 15) & ~(size_t)15;
    size_t table_bytes = (size_t)nbins * sizeof(float4);

    if (perm_bytes + table_bytes <= ws_size) {
        int*    perm  = (int*)d_ws;
        float4* table = (float4*)((char*)d_ws + perm_bytes);

        roi_sortkey<<<1, 1024, 0, stream>>>(rois, perm, R);
        roi_precompute<<<(nbins + 255) / 256, 256, 0, stream>>>(rois, table, nbins);
        roi_main<<<R * 8, 256, 0, stream>>>(feat, table, perm, out, R);
    } else {
        roi_fused<<<(total + 255) / 256, 256, 0, stream>>>(feat, rois, out, total);
    }
}

// Round 8
// 85.305 us; speedup vs baseline: 1.0010x; 1.0010x over previous
//
#include <hip/hip_runtime.h>

// RoIAlign: features (B=4, C=256, H=200, W=200) f32, rois (R,5) f32,
// out (R, C, 7, 7) f32.  SCALE=0.25, AH=AW=7, legacy (x2-x1+1) semantics.
//
// Round-8 = round-6 + paired taps: v00/v01 and v10/v11 loaded as single
// 8-byte loads (dwordx2) -> halves TA line-lookups (the measured wall).
//  - block = (roi, 32-channel group); 49-entry geometry table in LDS.
//  - table entry carries precomputed plane-0 word offset.
//  - each thread computes 2 outputs (ch, ch+16) sharing geometry.
//  - XCD channel affinity (bid&7), spatial roi sort, nontemporal stores.

#define C_     256
#define H_     200
#define W_     200
#define HW_    40000
#define NBIN   49
#define SCALE_ 0.25f
#define NKEY   256    // 4 batches x 8 y-tiles x 8 x-tiles

// ---------------- kernel 0: locality sort (counting sort, 256 buckets) -----
__global__ __launch_bounds__(1024) void roi_sortkey(
        const float* __restrict__ rois, int* __restrict__ perm, int R) {
    __shared__ int cnt[NKEY];
    __shared__ int off[NKEY];
    int t = threadIdx.x;
    if (t < NKEY) cnt[t] = 0;
    __syncthreads();
    for (int i = t; i < R; i += 1024) {
        const float* rr = rois + (size_t)i * 5;
        int b = ((int)rr[0]) & 3;
        float xc = (rr[1] + rr[3]) * 0.5f * SCALE_;
        float yc = (rr[2] + rr[4]) * 0.5f * SCALE_;
        int xt = min(7, max(0, (int)(xc * 0.04f)));
        int yt = min(7, max(0, (int)(yc * 0.04f)));
        atomicAdd(&cnt[(b << 6) | (yt << 3) | xt], 1);
    }
    __syncthreads();
    if (t == 0) {
        int s = 0;
        for (int k = 0; k < NKEY; ++k) { off[k] = s; s += cnt[k]; }
    }
    __syncthreads();
    for (int i = t; i < R; i += 1024) {
        const float* rr = rois + (size_t)i * 5;
        int b = ((int)rr[0]) & 3;
        float xc = (rr[1] + rr[3]) * 0.5f * SCALE_;
        float yc = (rr[2] + rr[4]) * 0.5f * SCALE_;
        int xt = min(7, max(0, (int)(xc * 0.04f)));
        int yt = min(7, max(0, (int)(yc * 0.04f)));
        int pos = atomicAdd(&off[(b << 6) | (yt << 3) | xt], 1);
        perm[pos] = i;
    }
}

// ---------------- kernel 1: per-(roi,bin) geometry table -------------------
// table[i] = { hr, wr, as_float(plane0 word offset), validf }
__global__ __launch_bounds__(256) void roi_precompute(
        const float* __restrict__ rois, float4* __restrict__ table, int nbins) {
    int i = blockIdx.x * 256 + threadIdx.x;
    if (i >= nbins) return;
    int r   = i / NBIN;
    int bin = i - r * NBIN;
    int ph  = bin / 7;
    int pw  = bin - ph * 7;

    float bf = rois[r * 5 + 0];
    float x1 = rois[r * 5 + 1] * SCALE_;
    float y1 = rois[r * 5 + 2] * SCALE_;
    float x2 = rois[r * 5 + 3] * SCALE_;
    float y2 = rois[r * 5 + 4] * SCALE_;

    float bin_h = fmaxf(y2 - y1 + 1.0f, 0.0f) * (1.0f / 6.0f);
    float bin_w = fmaxf(x2 - x1 + 1.0f, 0.0f) * (1.0f / 6.0f);

    float h = y1 + (float)ph * bin_h;
    float w = x1 + (float)pw * bin_w;

    bool valid = (h >= 0.0f) && (h < (float)H_) && (w >= 0.0f) && (w < (float)W_);

    float h0f = fmaxf(fminf(floorf(h), (float)(H_ - 2)), 0.0f);
    float w0f = fmaxf(fminf(floorf(w), (float)(W_ - 2)), 0.0f);
    float hr = h - h0f;
    float wr = w - w0f;
    int b  = (int)bf;
    int off0 = b * C_ * HW_ + (int)h0f * W_ + (int)w0f;   // < 2^31

    table[i] = make_float4(hr, wr, __int_as_float(off0), valid ? 1.0f : 0.0f);
}

// ---------------- kernel 2: main gather -------------------------------------
// grid = R*8 blocks; g = bid&7 (XCD affinity), pos = bid>>3, roi = perm[pos].
// Block covers channels [g*32, g*32+32): item o = ci*49+bin handles ch c0+ci
// and c0+ci+16 (2 outputs, shared geometry).  Taps loaded pairwise (8B).
__global__ __launch_bounds__(256) void roi_main(
        const float* __restrict__ feat, const float4* __restrict__ table,
        const int* __restrict__ perm, float* __restrict__ out, int R) {
    __shared__ float4 sT[NBIN];
    int bid = blockIdx.x;
    int g   = bid & 7;
    int pos = bid >> 3;
    int r   = perm[pos];
    int tid = threadIdx.x;
    if (tid < NBIN) sT[tid] = table[(size_t)r * NBIN + tid];
    __syncthreads();

    int c0 = g * 32;
    size_t outbase = ((size_t)r * C_ + c0) * NBIN;

    #pragma unroll
    for (int k = 0; k < 4; ++k) {
        int o = tid + k * 256;
        if (o < 16 * NBIN) {
            int ci  = o / NBIN;
            int bin = o - ci * NBIN;
            float4 e = sT[bin];
            float hr = e.x, wr = e.y, vf = e.w;
            int   off = __float_as_int(e.z) + (c0 + ci) * HW_;

            const float* pA = feat + off;             // ch = c0+ci
            const float* pB = pA + 16 * HW_;          // ch = c0+ci+16

            float2 a0, a1, b0, b1;                    // {v.0, v.1} pairs
            __builtin_memcpy(&a0, pA,       8);
            __builtin_memcpy(&a1, pA + W_,  8);
            __builtin_memcpy(&b0, pB,       8);
            __builtin_memcpy(&b1, pB + W_,  8);

            float at = fmaf(wr, a0.y - a0.x, a0.x);
            float ab = fmaf(wr, a1.y - a1.x, a1.x);
            float bt = fmaf(wr, b0.y - b0.x, b0.x);
            float bb = fmaf(wr, b1.y - b1.x, b1.x);
            float va = fmaf(hr, ab - at, at) * vf;
            float vb = fmaf(hr, bb - bt, bt) * vf;

            __builtin_nontemporal_store(va, &out[outbase + o]);
            __builtin_nontemporal_store(vb, &out[outbase + o + 16 * NBIN]);
        }
    }
}

// ---------------- fallback: fused (no workspace) ----------------------------
__global__ __launch_bounds__(256) void roi_fused(
        const float* __restrict__ feat, const float* __restrict__ rois,
        float* __restrict__ out, int total) {
    int idx = blockIdx.x * 256 + threadIdx.x;
    if (idx >= total) return;

    unsigned u   = (unsigned)idx;
    unsigned bin = u % (unsigned)NBIN;
    unsigned rc  = u / (unsigned)NBIN;
    unsigned c   = rc & 255u;
    unsigned r   = rc >> 8;
    int ph = bin / 7;
    int pw = bin - ph * 7;

    float bf = rois[r * 5 + 0];
    float x1 = rois[r * 5 + 1] * SCALE_;
    float y1 = rois[r * 5 + 2] * SCALE_;
    float x2 = rois[r * 5 + 3] * SCALE_;
    float y2 = rois[r * 5 + 4] * SCALE_;

    float roi_w = fmaxf(x2 - x1 + 1.0f, 0.0f);
    float roi_h = fmaxf(y2 - y1 + 1.0f, 0.0f);
    float h = y1 + (float)ph * (roi_h / 6.0f);
    float w = x1 + (float)pw * (roi_w / 6.0f);

    float valid = ((h >= 0.0f) && (h < (float)H_) && (w >= 0.0f) && (w < (float)W_))
                      ? 1.0f : 0.0f;

    float h0f = fmaxf(fminf(floorf(h), (float)(H_ - 2)), 0.0f);
    float w0f = fmaxf(fminf(floorf(w), (float)(W_ - 2)), 0.0f);
    int h0 = (int)h0f;
    int w0 = (int)w0f;
    float hr = h - h0f;
    float wr = w - w0f;
    int b = (int)bf;

    const float* p = feat + ((size_t)(b * C_ + (int)c)) * (size_t)HW_
                          + (size_t)(h0 * W_ + w0);
    float v00 = p[0];
    float v01 = p[1];
    float v10 = p[W_];
    float v11 = p[W_ + 1];

    float top = fmaf(wr, v01 - v00, v00);
    float bot = fmaf(wr, v11 - v10, v10);
    float val = fmaf(hr, bot - top, top);

    out[idx] = val * valid;
}

extern "C" void kernel_launch(void* const* d_in, const int* in_sizes, int n_in,
                              void* d_out, int out_size, void* d_ws, size_t ws_size,
                              hipStream_t stream) {
    const float* feat = (const float*)d_in[0];
    const float* rois = (const float*)d_in[1];
    float* out = (float*)d_out;

    int R     = in_sizes[1] / 5;
    int nbins = R * NBIN;
    int total = R * C_ * NBIN;   // == out_size

    // workspace layout: perm (R ints), then 16B-aligned table (R*49 float4)
    size_t perm_bytes  = ((size_t)R * sizeof(int) + 15) & ~(size_t)15;
    size_t table_bytes = (size_t)nbins * sizeof(float4);

    if (perm_bytes + table_bytes <= ws_size) {
        int*    perm  = (int*)d_ws;
        float4* table = (float4*)((char*)d_ws + perm_bytes);

        roi_sortkey<<<1, 1024, 0, stream>>>(rois, perm, R);
        roi_precompute<<<(nbins + 255) / 256, 256, 0, stream>>>(rois, table, nbins);
        roi_main<<<R * 8, 256, 0, stream>>>(feat, table, perm, out, R);
    } else {
        roi_fused<<<(total + 255) / 256, 256, 0, stream>>>(feat, rois, out, total);
    }
}